// Round 10
// baseline (299.692 us; speedup 1.0000x reference)
//
#include <hip/hip_runtime.h>
#include <hip/hip_bf16.h>

// GraphSAGE forward:
//   two-level binned CSR build -> wconv -> linear1 (MFMA) ->
//   3x fused layer kernel [per-block gather-mean into LDS + MFMA GEMM(norm,relu); layer 3 also
//   runs the W2 GEMM from LDS and writes the final output] -- h ping-pongs between two bf16 buffers.

#define NT 256
#define BATCH 4096        // edges per bin1 block (NT * 16)
#define SBCAP 8192        // slots per super-bucket region (mean 6378 for m=1.25M)
#define ASTRIDE 72        // aggS row stride in bf16 (16B-aligned rows: 144 B)

typedef __attribute__((ext_vector_type(8))) short bf16x8;
typedef __attribute__((ext_vector_type(4))) float f32x4;

__device__ __forceinline__ float bfbits2f(unsigned short b) {
    return __uint_as_float(((unsigned)b) << 16);
}
__device__ __forceinline__ unsigned short f2bfbits(float v) {
    __hip_bfloat16 b = __float2bfloat16(v);
    return *reinterpret_cast<unsigned short*>(&b);
}

// ---------------- CSR build: two-level binning (unchanged from R9) ----------------

__global__ __launch_bounds__(NT) void bin1_kernel(const int* __restrict__ src,
    const int* __restrict__ dst, int m, unsigned* __restrict__ gcur,
    unsigned* __restrict__ bins) {
    __shared__ unsigned hist[256];
    __shared__ unsigned gbase[256];
    const int t = threadIdx.x;
    const int base = blockIdx.x * BATCH;
    hist[t] = 0;
    __syncthreads();
    int d[16], s[16];
    const int e0 = base + t * 16;
    const bool full = (base + BATCH) <= m;
    if (full) {
        #pragma unroll
        for (int q = 0; q < 4; ++q) {
            const int4 dv = *(const int4*)&dst[e0 + q * 4];
            const int4 sv = *(const int4*)&src[e0 + q * 4];
            d[q*4+0]=dv.x; d[q*4+1]=dv.y; d[q*4+2]=dv.z; d[q*4+3]=dv.w;
            s[q*4+0]=sv.x; s[q*4+1]=sv.y; s[q*4+2]=sv.z; s[q*4+3]=sv.w;
        }
        #pragma unroll
        for (int q = 0; q < 16; ++q) atomicAdd(&hist[d[q] >> 9], 1u);
    } else {
        #pragma unroll
        for (int q = 0; q < 16; ++q) {
            const int e = e0 + q;
            if (e < m) { d[q] = dst[e]; s[q] = src[e]; atomicAdd(&hist[d[q] >> 9], 1u); }
            else d[q] = -1;
        }
    }
    __syncthreads();
    {
        const unsigned h = hist[t];
        gbase[t] = h ? atomicAdd(&gcur[t], h) : 0u;
        hist[t] = 0;                       // reuse as per-bucket cursor
    }
    __syncthreads();
    if (full) {
        #pragma unroll
        for (int q = 0; q < 16; ++q) {
            const int b = d[q] >> 9;
            const unsigned slot = gbase[b] + atomicAdd(&hist[b], 1u);
            bins[(size_t)b * SBCAP + slot] = ((unsigned)s[q] << 9) | (unsigned)(d[q] & 511);
        }
    } else {
        #pragma unroll
        for (int q = 0; q < 16; ++q) {
            if (d[q] >= 0) {
                const int b = d[q] >> 9;
                const unsigned slot = gbase[b] + atomicAdd(&hist[b], 1u);
                bins[(size_t)b * SBCAP + slot] = ((unsigned)s[q] << 9) | (unsigned)(d[q] & 511);
            }
        }
    }
}

__global__ void sbase_kernel(const unsigned* __restrict__ gcur, unsigned* __restrict__ sbase,
                             int* __restrict__ row_ptr, int n, int nsb, int m) {
    __shared__ unsigned wsum[4];
    const int t = threadIdx.x, lane = t & 63, wid = t >> 6;
    const unsigned v = (t < nsb) ? gcur[t] : 0u;
    unsigned x = v;
    #pragma unroll
    for (int o = 1; o < 64; o <<= 1) {
        const unsigned tt = __shfl_up(x, o, 64);
        if (lane >= o) x += tt;
    }
    if (lane == 63) wsum[wid] = x;
    __syncthreads();
    unsigned woff = 0;
    for (int w = 0; w < wid; ++w) woff += wsum[w];
    if (t < nsb) sbase[t] = woff + x - v;
    if (t == 0) row_ptr[n] = m;
}

__global__ __launch_bounds__(NT) void bin2_kernel(const unsigned* __restrict__ bins,
    const unsigned* __restrict__ gcur, const unsigned* __restrict__ sbase,
    int* __restrict__ row_ptr, int* __restrict__ csr, int n) {
    __shared__ unsigned hist[512];
    __shared__ unsigned off[512];
    __shared__ unsigned cur[512];
    __shared__ unsigned wsum[4];
    const int k = blockIdx.x;
    const int t = threadIdx.x;
    const int lane = t & 63, wid = t >> 6;
    const int cnt = (int)gcur[k];
    const unsigned sb = sbase[k];
    const unsigned* reg = bins + (size_t)k * SBCAP;
    hist[2*t] = 0; hist[2*t+1] = 0;
    __syncthreads();
    for (int i = t; i < cnt; i += NT) atomicAdd(&hist[reg[i] & 511u], 1u);
    __syncthreads();
    const unsigned v0 = hist[2*t], v1 = hist[2*t+1];
    const unsigned ps = v0 + v1;
    unsigned x = ps;
    #pragma unroll
    for (int o = 1; o < 64; o <<= 1) {
        const unsigned tt = __shfl_up(x, o, 64);
        if (lane >= o) x += tt;
    }
    if (lane == 63) wsum[wid] = x;
    __syncthreads();
    unsigned woff = 0;
    for (int w = 0; w < wid; ++w) woff += wsum[w];
    const unsigned excl = woff + x - ps;
    off[2*t] = excl; off[2*t+1] = excl + v0;
    cur[2*t] = 0; cur[2*t+1] = 0;
    const int node = k * 512 + 2 * t;
    if (node < n)     row_ptr[node]     = (int)(sb + excl);
    if (node + 1 < n) row_ptr[node + 1] = (int)(sb + excl + v0);
    __syncthreads();
    for (int i = t; i < cnt; i += NT) {
        const unsigned u = reg[i];
        const unsigned l = u & 511u;
        const unsigned r = atomicAdd(&cur[l], 1u);
        csr[sb + off[l] + r] = (int)(u >> 9);
    }
}

// ---------------- weight convert+transpose: Wt[col][k] bf16 ----------------

__global__ void wconv_kernel(const float* __restrict__ W1, const float* __restrict__ Wl,
                             const float* __restrict__ Wr, const float* __restrict__ W2,
                             unsigned short* __restrict__ out) {
    int i = blockIdx.x * blockDim.x + threadIdx.x;
    if (i >= 36864) return;
    float v;
    if (i < 8192) {
        const int col = i >> 7, k = i & 127;
        v = W1[k * 64 + col];
    } else if (i < 32768) {
        const int j = i - 8192;
        const int mm = j >> 13, r = j & 8191;
        const int isR = (r >> 12) & 1, q = r & 4095;
        const int col = q >> 6, k = q & 63;
        v = (isR ? Wr : Wl)[mm * 4096 + k * 64 + col];
    } else {
        const int q = i - 32768;
        const int col = q >> 6, k = q & 63;
        v = W2[k * 64 + col];
    }
    out[i] = f2bfbits(v);
}

// ---------------- linear1: h0 = bf16(x @ W1 + b1), MFMA, f32 A converted in-register ----------------

__global__ __launch_bounds__(NT) void lin1_kernel(
    const float* __restrict__ x, const unsigned short* __restrict__ W1t,
    const float* __restrict__ b1, unsigned short* __restrict__ hbf, int n) {
    const int t = threadIdx.x;
    const int lane = t & 63;
    const int w = t >> 6;
    const int c = lane & 15;
    const int g = lane >> 4;
    const int row0 = blockIdx.x * 128 + w * 32;

    f32x4 acc[2][4];
    #pragma unroll
    for (int i = 0; i < 2; ++i)
        #pragma unroll
        for (int j = 0; j < 4; ++j) { acc[i][j][0]=0.f; acc[i][j][1]=0.f; acc[i][j][2]=0.f; acc[i][j][3]=0.f; }

    int ra[2];
    #pragma unroll
    for (int rt = 0; rt < 2; ++rt) {
        const int r = row0 + rt * 16 + c;
        ra[rt] = (r < n) ? r : (n - 1);
    }

    #pragma unroll 1
    for (int kc = 0; kc < 128; kc += 32) {
        bf16x8 af[2];
        #pragma unroll
        for (int rt = 0; rt < 2; ++rt) {
            const float* p = &x[(size_t)ra[rt] * 128 + kc + g * 8];
            const float4 f0 = *(const float4*)p;
            const float4 f1 = *(const float4*)(p + 4);
            bf16x8 a;
            a[0] = (short)f2bfbits(f0.x); a[1] = (short)f2bfbits(f0.y);
            a[2] = (short)f2bfbits(f0.z); a[3] = (short)f2bfbits(f0.w);
            a[4] = (short)f2bfbits(f1.x); a[5] = (short)f2bfbits(f1.y);
            a[6] = (short)f2bfbits(f1.z); a[7] = (short)f2bfbits(f1.w);
            af[rt] = a;
        }
        #pragma unroll
        for (int ct = 0; ct < 4; ++ct) {
            const bf16x8 bw = *(const bf16x8*)&W1t[(size_t)(ct * 16 + c) * 128 + kc + g * 8];
            acc[0][ct] = __builtin_amdgcn_mfma_f32_16x16x32_bf16(af[0], bw, acc[0][ct], 0, 0, 0);
            acc[1][ct] = __builtin_amdgcn_mfma_f32_16x16x32_bf16(af[1], bw, acc[1][ct], 0, 0, 0);
        }
    }

    float bcol[4];
    #pragma unroll
    for (int ct = 0; ct < 4; ++ct) bcol[ct] = b1[ct * 16 + c];
    #pragma unroll
    for (int rt = 0; rt < 2; ++rt) {
        const int rbase = row0 + rt * 16 + g * 4;
        #pragma unroll
        for (int reg = 0; reg < 4; ++reg) {
            const int rr = rbase + reg;
            if (rr < n) {
                #pragma unroll
                for (int ct = 0; ct < 4; ++ct)
                    hbf[(size_t)rr * 64 + ct * 16 + c] = f2bfbits(acc[rt][ct][reg] + bcol[ct]);
            }
        }
    }
}

// ---------------- fused SAGE layer ----------------
// Phase A: each wave gather-means its 32 nodes into aggS (bf16, LDS).
// Phase B: MFMA GEMM acc = aggS@Wl + h@Wr + bl -> L2norm -> relu.
// LAST=0: write h' rows (bf16, other buffer).  LAST=1: h' -> LDS, then out = h'@W2 + b2 (f32).

template<int LAST>
__global__ __launch_bounds__(NT) void sage_fused(
    const unsigned short* __restrict__ hin,
    const int* __restrict__ row_ptr, const int* __restrict__ csr,
    const unsigned short* __restrict__ Wlt, const unsigned short* __restrict__ Wrt,
    const float* __restrict__ bl,
    const unsigned short* __restrict__ W2t, const float* __restrict__ b2,
    unsigned short* __restrict__ hout, float* __restrict__ out, int n) {
    __shared__ unsigned short aggS[128][ASTRIDE];   // 18 KB
    const int t = threadIdx.x;
    const int lane = t & 63;
    const int w = t >> 6;
    const int g = lane >> 4;
    const int c = lane & 15;
    const int tile0 = blockIdx.x * 128;

    // ---- Phase A: aggregate 32 nodes per wave ----
    for (int i = 0; i < 32; ++i) {
        const int node = tile0 + w * 32 + i;
        if (node >= n) break;                       // wave-uniform
        const int rs = row_ptr[node];
        const int re = row_ptr[node + 1];
        float a0 = 0.f, a1 = 0.f, a2 = 0.f, a3 = 0.f;
        int e = rs;
        for (; e + 16 <= re; e += 16) {
            const int s0 = csr[e + g];
            const int s1 = csr[e + 4 + g];
            const int s2 = csr[e + 8 + g];
            const int s3 = csr[e + 12 + g];
            const ushort4 v0 = *(const ushort4*)&hin[(size_t)s0 * 64 + c * 4];
            const ushort4 v1 = *(const ushort4*)&hin[(size_t)s1 * 64 + c * 4];
            const ushort4 v2 = *(const ushort4*)&hin[(size_t)s2 * 64 + c * 4];
            const ushort4 v3 = *(const ushort4*)&hin[(size_t)s3 * 64 + c * 4];
            a0 += (bfbits2f(v0.x) + bfbits2f(v1.x)) + (bfbits2f(v2.x) + bfbits2f(v3.x));
            a1 += (bfbits2f(v0.y) + bfbits2f(v1.y)) + (bfbits2f(v2.y) + bfbits2f(v3.y));
            a2 += (bfbits2f(v0.z) + bfbits2f(v1.z)) + (bfbits2f(v2.z) + bfbits2f(v3.z));
            a3 += (bfbits2f(v0.w) + bfbits2f(v1.w)) + (bfbits2f(v2.w) + bfbits2f(v3.w));
        }
        for (; e + 8 <= re; e += 8) {
            const int s0 = csr[e + g];
            const int s1 = csr[e + 4 + g];
            const ushort4 v0 = *(const ushort4*)&hin[(size_t)s0 * 64 + c * 4];
            const ushort4 v1 = *(const ushort4*)&hin[(size_t)s1 * 64 + c * 4];
            a0 += bfbits2f(v0.x) + bfbits2f(v1.x);
            a1 += bfbits2f(v0.y) + bfbits2f(v1.y);
            a2 += bfbits2f(v0.z) + bfbits2f(v1.z);
            a3 += bfbits2f(v0.w) + bfbits2f(v1.w);
        }
        for (; e + 4 <= re; e += 4) {
            const int s0 = csr[e + g];
            const ushort4 v0 = *(const ushort4*)&hin[(size_t)s0 * 64 + c * 4];
            a0 += bfbits2f(v0.x); a1 += bfbits2f(v0.y);
            a2 += bfbits2f(v0.z); a3 += bfbits2f(v0.w);
        }
        const int r = re - e;
        if (g < r) {
            const int s0 = csr[e + g];
            const ushort4 v0 = *(const ushort4*)&hin[(size_t)s0 * 64 + c * 4];
            a0 += bfbits2f(v0.x); a1 += bfbits2f(v0.y);
            a2 += bfbits2f(v0.z); a3 += bfbits2f(v0.w);
        }
        a0 += __shfl_xor(a0, 16, 64); a0 += __shfl_xor(a0, 32, 64);
        a1 += __shfl_xor(a1, 16, 64); a1 += __shfl_xor(a1, 32, 64);
        a2 += __shfl_xor(a2, 16, 64); a2 += __shfl_xor(a2, 32, 64);
        a3 += __shfl_xor(a3, 16, 64); a3 += __shfl_xor(a3, 32, 64);
        if (g == 0) {
            const float inv = (re > rs) ? (1.0f / (float)(re - rs)) : 0.0f;
            ushort4 o;
            o.x = f2bfbits(a0 * inv); o.y = f2bfbits(a1 * inv);
            o.z = f2bfbits(a2 * inv); o.w = f2bfbits(a3 * inv);
            *(ushort4*)&aggS[w * 32 + i][c * 4] = o;
        }
    }
    __syncthreads();

    // ---- Phase B: GEMM acc = aggS@Wl + hin@Wr ----
    f32x4 acc[2][4];
    #pragma unroll
    for (int i = 0; i < 2; ++i)
        #pragma unroll
        for (int j = 0; j < 4; ++j) { acc[i][j][0]=0.f; acc[i][j][1]=0.f; acc[i][j][2]=0.f; acc[i][j][3]=0.f; }

    int ra[2];
    #pragma unroll
    for (int rt = 0; rt < 2; ++rt) {
        const int r = tile0 + w * 32 + rt * 16 + c;
        ra[rt] = (r < n) ? r : (n - 1);
    }

    #pragma unroll
    for (int kc = 0; kc < 64; kc += 32) {
        bf16x8 a1[2], a2[2];
        #pragma unroll
        for (int rt = 0; rt < 2; ++rt) {
            a1[rt] = *(const bf16x8*)&aggS[w * 32 + rt * 16 + c][kc + g * 8];
            a2[rt] = *(const bf16x8*)&hin[(size_t)ra[rt] * 64 + kc + g * 8];
        }
        #pragma unroll
        for (int ct = 0; ct < 4; ++ct) {
            const bf16x8 bw1 = *(const bf16x8*)&Wlt[(size_t)(ct * 16 + c) * 64 + kc + g * 8];
            const bf16x8 bw2 = *(const bf16x8*)&Wrt[(size_t)(ct * 16 + c) * 64 + kc + g * 8];
            acc[0][ct] = __builtin_amdgcn_mfma_f32_16x16x32_bf16(a1[0], bw1, acc[0][ct], 0, 0, 0);
            acc[0][ct] = __builtin_amdgcn_mfma_f32_16x16x32_bf16(a2[0], bw2, acc[0][ct], 0, 0, 0);
            acc[1][ct] = __builtin_amdgcn_mfma_f32_16x16x32_bf16(a1[1], bw1, acc[1][ct], 0, 0, 0);
            acc[1][ct] = __builtin_amdgcn_mfma_f32_16x16x32_bf16(a2[1], bw2, acc[1][ct], 0, 0, 0);
        }
    }

    float bcol[4];
    #pragma unroll
    for (int ct = 0; ct < 4; ++ct) bcol[ct] = bl[ct * 16 + c];

    #pragma unroll
    for (int rt = 0; rt < 2; ++rt) {
        #pragma unroll
        for (int ct = 0; ct < 4; ++ct)
            #pragma unroll
            for (int reg = 0; reg < 4; ++reg) acc[rt][ct][reg] += bcol[ct];
        #pragma unroll
        for (int reg = 0; reg < 4; ++reg) {
            float ss = 0.f;
            #pragma unroll
            for (int ct = 0; ct < 4; ++ct) ss += acc[rt][ct][reg] * acc[rt][ct][reg];
            ss += __shfl_xor(ss, 1, 64);
            ss += __shfl_xor(ss, 2, 64);
            ss += __shfl_xor(ss, 4, 64);
            ss += __shfl_xor(ss, 8, 64);
            const float inv = 1.0f / fmaxf(sqrtf(ss), 1e-12f);
            #pragma unroll
            for (int ct = 0; ct < 4; ++ct)
                acc[rt][ct][reg] = fmaxf(acc[rt][ct][reg] * inv, 0.0f);
        }
    }

    if (!LAST) {
        #pragma unroll
        for (int rt = 0; rt < 2; ++rt) {
            const int rbase = tile0 + w * 32 + rt * 16 + g * 4;
            #pragma unroll
            for (int reg = 0; reg < 4; ++reg) {
                const int rr = rbase + reg;
                if (rr < n) {
                    #pragma unroll
                    for (int ct = 0; ct < 4; ++ct)
                        hout[(size_t)rr * 64 + ct * 16 + c] = f2bfbits(acc[rt][ct][reg]);
                }
            }
        }
    } else {
        // h3 tile -> LDS (reuse aggS), then out = h3 @ W2 + b2
        __syncthreads();   // everyone done reading aggS as agg
        #pragma unroll
        for (int rt = 0; rt < 2; ++rt) {
            #pragma unroll
            for (int reg = 0; reg < 4; ++reg) {
                const int lr = w * 32 + rt * 16 + g * 4 + reg;
                #pragma unroll
                for (int ct = 0; ct < 4; ++ct)
                    aggS[lr][ct * 16 + c] = f2bfbits(acc[rt][ct][reg]);
            }
        }
        __syncthreads();
        f32x4 acc2[2][4];
        #pragma unroll
        for (int i = 0; i < 2; ++i)
            #pragma unroll
            for (int j = 0; j < 4; ++j) { acc2[i][j][0]=0.f; acc2[i][j][1]=0.f; acc2[i][j][2]=0.f; acc2[i][j][3]=0.f; }
        #pragma unroll
        for (int kc = 0; kc < 64; kc += 32) {
            bf16x8 af[2];
            #pragma unroll
            for (int rt = 0; rt < 2; ++rt)
                af[rt] = *(const bf16x8*)&aggS[w * 32 + rt * 16 + c][kc + g * 8];
            #pragma unroll
            for (int ct = 0; ct < 4; ++ct) {
                const bf16x8 bw = *(const bf16x8*)&W2t[(size_t)(ct * 16 + c) * 64 + kc + g * 8];
                acc2[0][ct] = __builtin_amdgcn_mfma_f32_16x16x32_bf16(af[0], bw, acc2[0][ct], 0, 0, 0);
                acc2[1][ct] = __builtin_amdgcn_mfma_f32_16x16x32_bf16(af[1], bw, acc2[1][ct], 0, 0, 0);
            }
        }
        float b2c[4];
        #pragma unroll
        for (int ct = 0; ct < 4; ++ct) b2c[ct] = b2[ct * 16 + c];
        #pragma unroll
        for (int rt = 0; rt < 2; ++rt) {
            const int rbase = tile0 + w * 32 + rt * 16 + g * 4;
            #pragma unroll
            for (int reg = 0; reg < 4; ++reg) {
                const int rr = rbase + reg;
                if (rr < n) {
                    #pragma unroll
                    for (int ct = 0; ct < 4; ++ct)
                        out[(size_t)rr * 64 + ct * 16 + c] = acc2[rt][ct][reg] + b2c[ct];
                }
            }
        }
    }
}

// ---------------- launch ----------------

extern "C" void kernel_launch(void* const* d_in, const int* in_sizes, int n_in,
                              void* d_out, int out_size, void* d_ws, size_t ws_size,
                              hipStream_t stream) {
    const float* x  = (const float*)d_in[0];
    const int*   ei = (const int*)  d_in[1];
    const float* W1 = (const float*)d_in[2];
    const float* b1 = (const float*)d_in[3];
    const float* Wl = (const float*)d_in[4];
    const float* bl = (const float*)d_in[5];
    const float* Wr = (const float*)d_in[6];
    const float* W2 = (const float*)d_in[7];
    const float* b2 = (const float*)d_in[8];
    float* out = (float*)d_out;

    const int n = in_sizes[0] / 128;   // 100000
    const int m = in_sizes[1] / 2;     // 1250000
    const int* src = ei;
    const int* dst = ei + m;

    const int nsb = (n + 511) >> 9;    // 196 super-buckets (<= 256)

    char* ws = (char*)d_ws;
    size_t off = 0;
    auto alloc = [&](size_t bytes) -> void* {
        void* p = ws + off;
        off = (off + bytes + 255) & ~(size_t)255;
        return p;
    };
    unsigned short* hA      = (unsigned short*)alloc((size_t)n * 64 * 2);
    unsigned short* hB      = (unsigned short*)alloc((size_t)n * 64 * 2);
    int*            row_ptr = (int*)alloc((size_t)(n + 1) * sizeof(int));
    unsigned*       gcur    = (unsigned*)alloc((size_t)nsb * 4);
    unsigned*       sbase   = (unsigned*)alloc((size_t)(nsb + 1) * 4);
    unsigned*       bins    = (unsigned*)alloc((size_t)nsb * SBCAP * 4);
    int*            csr     = (int*)alloc((size_t)m * 4);
    unsigned short* wt      = (unsigned short*)alloc(36864 * 2);

    const unsigned short* W1t = wt;
    const unsigned short* W2t = wt + 32768;

    hipMemsetAsync(gcur, 0, (size_t)nsb * 4, stream);

    const int nb1 = (m + BATCH - 1) / BATCH;   // 306
    const int gtiles = (n + 127) / 128;        // 782

    wconv_kernel<<<144, NT, 0, stream>>>(W1, Wl, Wr, W2, wt);

    // h0 = x @ W1 + b1 -> hA
    lin1_kernel<<<gtiles, NT, 0, stream>>>(x, W1t, b1, hA, n);

    // two-level binned CSR build
    bin1_kernel<<<nb1, NT, 0, stream>>>(src, dst, m, gcur, bins);
    sbase_kernel<<<1, 256, 0, stream>>>(gcur, sbase, row_ptr, n, nsb, m);
    bin2_kernel<<<nsb, NT, 0, stream>>>(bins, gcur, sbase, row_ptr, csr, n);

    // layer 1: hA -> hB ; layer 2: hB -> hA ; layer 3 (+lin2): hA -> out
    sage_fused<0><<<gtiles, NT, 0, stream>>>(hA, row_ptr, csr,
                                             wt + 8192, wt + 8192 + 4096, bl,
                                             nullptr, nullptr, hB, nullptr, n);
    sage_fused<0><<<gtiles, NT, 0, stream>>>(hB, row_ptr, csr,
                                             wt + 8192 + 8192, wt + 8192 + 8192 + 4096, bl + 64,
                                             nullptr, nullptr, hA, nullptr, n);
    sage_fused<1><<<gtiles, NT, 0, stream>>>(hA, row_ptr, csr,
                                             wt + 8192 + 16384, wt + 8192 + 16384 + 4096, bl + 128,
                                             W2t, b2, nullptr, out, n);
}

// Round 11
// 223.645 us; speedup vs baseline: 1.3400x; 1.3400x over previous
//
#include <hip/hip_runtime.h>
#include <hip/hip_bf16.h>

// GraphSAGE forward (R11 = R9 structure + 8-slot agg + lin2 fused into layer-3 GEMM):
//   two-level binned CSR build -> wconv -> lin1 (MFMA) ->
//   3x [agg (8-edge-slot gather-mean, bf16) + MFMA GEMM(norm,relu)]; layer-3 GEMM also does W2.

#define NT 256
#define BATCH 4096        // edges per bin1 block (NT * 16)
#define SBCAP 8192        // slots per super-bucket region (mean 6378 for m=1.25M)
#define HSTRIDE 72        // h3 LDS tile row stride (bf16): 144 B rows, 16B-aligned, 2-way banks (free)

typedef __attribute__((ext_vector_type(8))) short bf16x8;
typedef __attribute__((ext_vector_type(8))) unsigned short u16x8;
typedef __attribute__((ext_vector_type(4))) float f32x4;

__device__ __forceinline__ float bfbits2f(unsigned short b) {
    return __uint_as_float(((unsigned)b) << 16);
}
__device__ __forceinline__ unsigned short f2bfbits(float v) {
    __hip_bfloat16 b = __float2bfloat16(v);
    return *reinterpret_cast<unsigned short*>(&b);
}

// ---------------- CSR build: two-level binning ----------------

__global__ __launch_bounds__(NT) void bin1_kernel(const int* __restrict__ src,
    const int* __restrict__ dst, int m, unsigned* __restrict__ gcur,
    unsigned* __restrict__ bins) {
    __shared__ unsigned hist[256];
    __shared__ unsigned gbase[256];
    const int t = threadIdx.x;
    const int base = blockIdx.x * BATCH;
    hist[t] = 0;
    __syncthreads();
    int d[16], s[16];
    const int e0 = base + t * 16;
    const bool full = (base + BATCH) <= m;
    if (full) {
        #pragma unroll
        for (int q = 0; q < 4; ++q) {
            const int4 dv = *(const int4*)&dst[e0 + q * 4];
            const int4 sv = *(const int4*)&src[e0 + q * 4];
            d[q*4+0]=dv.x; d[q*4+1]=dv.y; d[q*4+2]=dv.z; d[q*4+3]=dv.w;
            s[q*4+0]=sv.x; s[q*4+1]=sv.y; s[q*4+2]=sv.z; s[q*4+3]=sv.w;
        }
        #pragma unroll
        for (int q = 0; q < 16; ++q) atomicAdd(&hist[d[q] >> 9], 1u);
    } else {
        #pragma unroll
        for (int q = 0; q < 16; ++q) {
            const int e = e0 + q;
            if (e < m) { d[q] = dst[e]; s[q] = src[e]; atomicAdd(&hist[d[q] >> 9], 1u); }
            else d[q] = -1;
        }
    }
    __syncthreads();
    {
        const unsigned h = hist[t];
        gbase[t] = h ? atomicAdd(&gcur[t], h) : 0u;
        hist[t] = 0;                       // reuse as per-bucket cursor
    }
    __syncthreads();
    if (full) {
        #pragma unroll
        for (int q = 0; q < 16; ++q) {
            const int b = d[q] >> 9;
            const unsigned slot = gbase[b] + atomicAdd(&hist[b], 1u);
            bins[(size_t)b * SBCAP + slot] = ((unsigned)s[q] << 9) | (unsigned)(d[q] & 511);
        }
    } else {
        #pragma unroll
        for (int q = 0; q < 16; ++q) {
            if (d[q] >= 0) {
                const int b = d[q] >> 9;
                const unsigned slot = gbase[b] + atomicAdd(&hist[b], 1u);
                bins[(size_t)b * SBCAP + slot] = ((unsigned)s[q] << 9) | (unsigned)(d[q] & 511);
            }
        }
    }
}

__global__ void sbase_kernel(const unsigned* __restrict__ gcur, unsigned* __restrict__ sbase,
                             int* __restrict__ row_ptr, int n, int nsb, int m) {
    __shared__ unsigned wsum[4];
    const int t = threadIdx.x, lane = t & 63, wid = t >> 6;
    const unsigned v = (t < nsb) ? gcur[t] : 0u;
    unsigned x = v;
    #pragma unroll
    for (int o = 1; o < 64; o <<= 1) {
        const unsigned tt = __shfl_up(x, o, 64);
        if (lane >= o) x += tt;
    }
    if (lane == 63) wsum[wid] = x;
    __syncthreads();
    unsigned woff = 0;
    for (int w = 0; w < wid; ++w) woff += wsum[w];
    if (t < nsb) sbase[t] = woff + x - v;
    if (t == 0) row_ptr[n] = m;
}

__global__ __launch_bounds__(NT) void bin2_kernel(const unsigned* __restrict__ bins,
    const unsigned* __restrict__ gcur, const unsigned* __restrict__ sbase,
    int* __restrict__ row_ptr, int* __restrict__ csr, int n) {
    __shared__ unsigned hist[512];
    __shared__ unsigned off[512];
    __shared__ unsigned cur[512];
    __shared__ unsigned wsum[4];
    const int k = blockIdx.x;
    const int t = threadIdx.x;
    const int lane = t & 63, wid = t >> 6;
    const int cnt = (int)gcur[k];
    const unsigned sb = sbase[k];
    const unsigned* reg = bins + (size_t)k * SBCAP;
    hist[2*t] = 0; hist[2*t+1] = 0;
    __syncthreads();
    for (int i = t; i < cnt; i += NT) atomicAdd(&hist[reg[i] & 511u], 1u);
    __syncthreads();
    const unsigned v0 = hist[2*t], v1 = hist[2*t+1];
    const unsigned ps = v0 + v1;
    unsigned x = ps;
    #pragma unroll
    for (int o = 1; o < 64; o <<= 1) {
        const unsigned tt = __shfl_up(x, o, 64);
        if (lane >= o) x += tt;
    }
    if (lane == 63) wsum[wid] = x;
    __syncthreads();
    unsigned woff = 0;
    for (int w = 0; w < wid; ++w) woff += wsum[w];
    const unsigned excl = woff + x - ps;
    off[2*t] = excl; off[2*t+1] = excl + v0;
    cur[2*t] = 0; cur[2*t+1] = 0;
    const int node = k * 512 + 2 * t;
    if (node < n)     row_ptr[node]     = (int)(sb + excl);
    if (node + 1 < n) row_ptr[node + 1] = (int)(sb + excl + v0);
    __syncthreads();
    for (int i = t; i < cnt; i += NT) {
        const unsigned u = reg[i];
        const unsigned l = u & 511u;
        const unsigned r = atomicAdd(&cur[l], 1u);
        csr[sb + off[l] + r] = (int)(u >> 9);
    }
}

// ---------------- weight convert+transpose: Wt[col][k] bf16 ----------------

__global__ void wconv_kernel(const float* __restrict__ W1, const float* __restrict__ Wl,
                             const float* __restrict__ Wr, const float* __restrict__ W2,
                             unsigned short* __restrict__ out) {
    int i = blockIdx.x * blockDim.x + threadIdx.x;
    if (i >= 36864) return;
    float v;
    if (i < 8192) {
        const int col = i >> 7, k = i & 127;
        v = W1[k * 64 + col];
    } else if (i < 32768) {
        const int j = i - 8192;
        const int mm = j >> 13, r = j & 8191;
        const int isR = (r >> 12) & 1, q = r & 4095;
        const int col = q >> 6, k = q & 63;
        v = (isR ? Wr : Wl)[mm * 4096 + k * 64 + col];
    } else {
        const int q = i - 32768;
        const int col = q >> 6, k = q & 63;
        v = W2[k * 64 + col];
    }
    out[i] = f2bfbits(v);
}

// ---------------- aggregation: aggB[node] = bf16(mean over in-edges of h[src]) ----------------
// lane split: g=lane>>3 (8 edge slots), c=lane&7 (8 cols each, ushort8 = 16B per lane).
// One wave-load instruction covers 8 edges x 128 B = 1 KB.

__global__ __launch_bounds__(NT) void agg_kernel(const unsigned short* __restrict__ h,
    const int* __restrict__ row_ptr, const int* __restrict__ csr,
    unsigned short* __restrict__ aggB, int n) {
    const int t = threadIdx.x;
    const int lane = t & 63;
    const int g = lane >> 3;
    const int c = lane & 7;
    const int gw = (blockIdx.x * NT + t) >> 6;
    const int nw = (gridDim.x * NT) >> 6;
    for (int node = gw; node < n; node += nw) {
        const int rs = row_ptr[node];
        const int re = row_ptr[node + 1];
        float a0=0.f,a1=0.f,a2=0.f,a3=0.f,a4=0.f,a5=0.f,a6=0.f,a7=0.f;
        int e = rs;
        for (; e + 16 <= re; e += 16) {
            const int s0 = csr[e + g];
            const int s1 = csr[e + 8 + g];
            const u16x8 v0 = *(const u16x8*)&h[(size_t)s0 * 64 + c * 8];
            const u16x8 v1 = *(const u16x8*)&h[(size_t)s1 * 64 + c * 8];
            a0 += bfbits2f(v0[0]) + bfbits2f(v1[0]);
            a1 += bfbits2f(v0[1]) + bfbits2f(v1[1]);
            a2 += bfbits2f(v0[2]) + bfbits2f(v1[2]);
            a3 += bfbits2f(v0[3]) + bfbits2f(v1[3]);
            a4 += bfbits2f(v0[4]) + bfbits2f(v1[4]);
            a5 += bfbits2f(v0[5]) + bfbits2f(v1[5]);
            a6 += bfbits2f(v0[6]) + bfbits2f(v1[6]);
            a7 += bfbits2f(v0[7]) + bfbits2f(v1[7]);
        }
        for (; e + 8 <= re; e += 8) {
            const int s0 = csr[e + g];
            const u16x8 v0 = *(const u16x8*)&h[(size_t)s0 * 64 + c * 8];
            a0 += bfbits2f(v0[0]); a1 += bfbits2f(v0[1]);
            a2 += bfbits2f(v0[2]); a3 += bfbits2f(v0[3]);
            a4 += bfbits2f(v0[4]); a5 += bfbits2f(v0[5]);
            a6 += bfbits2f(v0[6]); a7 += bfbits2f(v0[7]);
        }
        const int r = re - e;
        if (g < r) {
            const int s0 = csr[e + g];
            const u16x8 v0 = *(const u16x8*)&h[(size_t)s0 * 64 + c * 8];
            a0 += bfbits2f(v0[0]); a1 += bfbits2f(v0[1]);
            a2 += bfbits2f(v0[2]); a3 += bfbits2f(v0[3]);
            a4 += bfbits2f(v0[4]); a5 += bfbits2f(v0[5]);
            a6 += bfbits2f(v0[6]); a7 += bfbits2f(v0[7]);
        }
        // reduce across the 8 edge-slots (lane bits 3,4,5)
        #pragma unroll
        for (int o = 8; o < 64; o <<= 1) {
            a0 += __shfl_xor(a0, o, 64); a1 += __shfl_xor(a1, o, 64);
            a2 += __shfl_xor(a2, o, 64); a3 += __shfl_xor(a3, o, 64);
            a4 += __shfl_xor(a4, o, 64); a5 += __shfl_xor(a5, o, 64);
            a6 += __shfl_xor(a6, o, 64); a7 += __shfl_xor(a7, o, 64);
        }
        if (g == 0) {
            const float inv = (re > rs) ? (1.0f / (float)(re - rs)) : 0.0f;
            u16x8 o;
            o[0] = f2bfbits(a0 * inv); o[1] = f2bfbits(a1 * inv);
            o[2] = f2bfbits(a2 * inv); o[3] = f2bfbits(a3 * inv);
            o[4] = f2bfbits(a4 * inv); o[5] = f2bfbits(a5 * inv);
            o[6] = f2bfbits(a6 * inv); o[7] = f2bfbits(a7 * inv);
            *(u16x8*)&aggB[(size_t)node * 64 + c * 8] = o;
        }
    }
}

// ---------------- MFMA GEMM: C = A1@W1 [+ A2@W2] + bias; optional norm; LAST: + (C@W2t2 + b2) ----------------
// block = 4 waves, wave = 32 rows x 64 cols (2 row-tiles x 4 col-tiles of 16x16x32 mfma).
// C/D: col = lane&15, row = (lane>>4)*4 + reg.

template<int A1F32, int LAST>
__global__ __launch_bounds__(NT) void gemm_mfma(
    const float* __restrict__ A1f, const unsigned short* __restrict__ A1b,
    int ldA1, int K1, const unsigned short* __restrict__ W1t,
    const unsigned short* __restrict__ A2b, const unsigned short* __restrict__ W2t,
    const float* __restrict__ bias, float* __restrict__ outF,
    unsigned short* __restrict__ outB, int n, int do_norm,
    const unsigned short* __restrict__ W2t2, const float* __restrict__ b2) {
    const int t = threadIdx.x;
    const int lane = t & 63;
    const int w = t >> 6;
    const int r16 = lane & 15;
    const int g = lane >> 4;
    const int row0 = blockIdx.x * 128 + w * 32;

    f32x4 acc[2][4];
    #pragma unroll
    for (int i = 0; i < 2; ++i)
        #pragma unroll
        for (int j = 0; j < 4; ++j) {
            acc[i][j][0] = 0.f; acc[i][j][1] = 0.f; acc[i][j][2] = 0.f; acc[i][j][3] = 0.f;
        }

    int ra[2];
    #pragma unroll
    for (int rt = 0; rt < 2; ++rt) {
        int r = row0 + rt * 16 + r16;
        ra[rt] = (r < n) ? r : (n - 1);
    }

    #pragma unroll 1
    for (int kc = 0; kc < K1; kc += 32) {
        bf16x8 af[2];
        #pragma unroll
        for (int rt = 0; rt < 2; ++rt) {
            if (A1F32) {
                const float* p = &A1f[(size_t)ra[rt] * ldA1 + kc + g * 8];
                const float4 f0 = *(const float4*)p;
                const float4 f1 = *(const float4*)(p + 4);
                bf16x8 a;
                a[0] = (short)f2bfbits(f0.x); a[1] = (short)f2bfbits(f0.y);
                a[2] = (short)f2bfbits(f0.z); a[3] = (short)f2bfbits(f0.w);
                a[4] = (short)f2bfbits(f1.x); a[5] = (short)f2bfbits(f1.y);
                a[6] = (short)f2bfbits(f1.z); a[7] = (short)f2bfbits(f1.w);
                af[rt] = a;
            } else {
                af[rt] = *(const bf16x8*)&A1b[(size_t)ra[rt] * ldA1 + kc + g * 8];
            }
        }
        #pragma unroll
        for (int ct = 0; ct < 4; ++ct) {
            const bf16x8 bw = *(const bf16x8*)&W1t[(size_t)(ct * 16 + r16) * K1 + kc + g * 8];
            acc[0][ct] = __builtin_amdgcn_mfma_f32_16x16x32_bf16(af[0], bw, acc[0][ct], 0, 0, 0);
            acc[1][ct] = __builtin_amdgcn_mfma_f32_16x16x32_bf16(af[1], bw, acc[1][ct], 0, 0, 0);
        }
    }
    if (A2b) {
        #pragma unroll 1
        for (int kc = 0; kc < 64; kc += 32) {
            bf16x8 af[2];
            #pragma unroll
            for (int rt = 0; rt < 2; ++rt)
                af[rt] = *(const bf16x8*)&A2b[(size_t)ra[rt] * 64 + kc + g * 8];
            #pragma unroll
            for (int ct = 0; ct < 4; ++ct) {
                const bf16x8 bw = *(const bf16x8*)&W2t[(size_t)(ct * 16 + r16) * 64 + kc + g * 8];
                acc[0][ct] = __builtin_amdgcn_mfma_f32_16x16x32_bf16(af[0], bw, acc[0][ct], 0, 0, 0);
                acc[1][ct] = __builtin_amdgcn_mfma_f32_16x16x32_bf16(af[1], bw, acc[1][ct], 0, 0, 0);
            }
        }
    }

    float bcol[4];
    #pragma unroll
    for (int ct = 0; ct < 4; ++ct) bcol[ct] = bias[ct * 16 + r16];

    #pragma unroll
    for (int rt = 0; rt < 2; ++rt) {
        #pragma unroll
        for (int ct = 0; ct < 4; ++ct)
            #pragma unroll
            for (int reg = 0; reg < 4; ++reg) acc[rt][ct][reg] += bcol[ct];

        if (do_norm) {
            #pragma unroll
            for (int reg = 0; reg < 4; ++reg) {
                float ss = 0.f;
                #pragma unroll
                for (int ct = 0; ct < 4; ++ct) ss += acc[rt][ct][reg] * acc[rt][ct][reg];
                ss += __shfl_xor(ss, 1, 64);
                ss += __shfl_xor(ss, 2, 64);
                ss += __shfl_xor(ss, 4, 64);
                ss += __shfl_xor(ss, 8, 64);
                const float inv = 1.0f / fmaxf(sqrtf(ss), 1e-12f);
                #pragma unroll
                for (int ct = 0; ct < 4; ++ct)
                    acc[rt][ct][reg] = fmaxf(acc[rt][ct][reg] * inv, 0.0f);
            }
        }
    }

    if constexpr (!LAST) {
        #pragma unroll
        for (int rt = 0; rt < 2; ++rt) {
            const int rbase = row0 + rt * 16 + g * 4;
            #pragma unroll
            for (int reg = 0; reg < 4; ++reg) {
                const int rr = rbase + reg;
                if (rr < n) {
                    if (outB) {
                        #pragma unroll
                        for (int ct = 0; ct < 4; ++ct)
                            outB[(size_t)rr * 64 + ct * 16 + r16] = f2bfbits(acc[rt][ct][reg]);
                    } else {
                        #pragma unroll
                        for (int ct = 0; ct < 4; ++ct)
                            outF[(size_t)rr * 64 + ct * 16 + r16] = acc[rt][ct][reg];
                    }
                }
            }
        }
    } else {
        // stage h3 tile in LDS, then out = h3 @ W2t2 + b2 (f32)
        __shared__ unsigned short h3S[128][HSTRIDE];   // 18 KB
        #pragma unroll
        for (int rt = 0; rt < 2; ++rt) {
            #pragma unroll
            for (int reg = 0; reg < 4; ++reg) {
                const int lr = w * 32 + rt * 16 + g * 4 + reg;
                #pragma unroll
                for (int ct = 0; ct < 4; ++ct)
                    h3S[lr][ct * 16 + r16] = f2bfbits(acc[rt][ct][reg]);
            }
        }
        __syncthreads();
        f32x4 acc2[2][4];
        #pragma unroll
        for (int i = 0; i < 2; ++i)
            #pragma unroll
            for (int j = 0; j < 4; ++j) { acc2[i][j][0]=0.f; acc2[i][j][1]=0.f; acc2[i][j][2]=0.f; acc2[i][j][3]=0.f; }
        #pragma unroll
        for (int kc = 0; kc < 64; kc += 32) {
            bf16x8 af[2];
            #pragma unroll
            for (int rt = 0; rt < 2; ++rt)
                af[rt] = *(const bf16x8*)&h3S[w * 32 + rt * 16 + r16][kc + g * 8];
            #pragma unroll
            for (int ct = 0; ct < 4; ++ct) {
                const bf16x8 bw = *(const bf16x8*)&W2t2[(size_t)(ct * 16 + r16) * 64 + kc + g * 8];
                acc2[0][ct] = __builtin_amdgcn_mfma_f32_16x16x32_bf16(af[0], bw, acc2[0][ct], 0, 0, 0);
                acc2[1][ct] = __builtin_amdgcn_mfma_f32_16x16x32_bf16(af[1], bw, acc2[1][ct], 0, 0, 0);
            }
        }
        float b2c[4];
        #pragma unroll
        for (int ct = 0; ct < 4; ++ct) b2c[ct] = b2[ct * 16 + r16];
        #pragma unroll
        for (int rt = 0; rt < 2; ++rt) {
            const int rbase = row0 + rt * 16 + g * 4;
            #pragma unroll
            for (int reg = 0; reg < 4; ++reg) {
                const int rr = rbase + reg;
                if (rr < n) {
                    #pragma unroll
                    for (int ct = 0; ct < 4; ++ct)
                        outF[(size_t)rr * 64 + ct * 16 + r16] = acc2[rt][ct][reg] + b2c[ct];
                }
            }
        }
    }
}

// ---------------- launch ----------------

extern "C" void kernel_launch(void* const* d_in, const int* in_sizes, int n_in,
                              void* d_out, int out_size, void* d_ws, size_t ws_size,
                              hipStream_t stream) {
    const float* x  = (const float*)d_in[0];
    const int*   ei = (const int*)  d_in[1];
    const float* W1 = (const float*)d_in[2];
    const float* b1 = (const float*)d_in[3];
    const float* Wl = (const float*)d_in[4];
    const float* bl = (const float*)d_in[5];
    const float* Wr = (const float*)d_in[6];
    const float* W2 = (const float*)d_in[7];
    const float* b2 = (const float*)d_in[8];
    float* out = (float*)d_out;

    const int n = in_sizes[0] / 128;   // 100000
    const int m = in_sizes[1] / 2;     // 1250000
    const int* src = ei;
    const int* dst = ei + m;

    const int nsb = (n + 511) >> 9;    // 196 super-buckets (<= 256)

    char* ws = (char*)d_ws;
    size_t off = 0;
    auto alloc = [&](size_t bytes) -> void* {
        void* p = ws + off;
        off = (off + bytes + 255) & ~(size_t)255;
        return p;
    };
    unsigned short* aggB    = (unsigned short*)alloc((size_t)n * 64 * 2);
    unsigned short* hbf     = (unsigned short*)alloc((size_t)n * 64 * 2);
    int*            row_ptr = (int*)alloc((size_t)(n + 1) * sizeof(int));
    unsigned*       gcur    = (unsigned*)alloc((size_t)nsb * 4);
    unsigned*       sbase   = (unsigned*)alloc((size_t)(nsb + 1) * 4);
    unsigned*       bins    = (unsigned*)alloc((size_t)nsb * SBCAP * 4);
    int*            csr     = (int*)alloc((size_t)m * 4);
    unsigned short* wt      = (unsigned short*)alloc(36864 * 2);

    const unsigned short* W1t = wt;
    const unsigned short* W2t = wt + 32768;

    hipMemsetAsync(gcur, 0, (size_t)nsb * 4, stream);

    const int nb1 = (m + BATCH - 1) / BATCH;   // 306
    const int gtiles = (n + 127) / 128;        // 782

    wconv_kernel<<<144, NT, 0, stream>>>(W1, Wl, Wr, W2, wt);

    // h0 = x @ W1 + b1 -> hbf (bf16)
    gemm_mfma<1, 0><<<gtiles, NT, 0, stream>>>(x, nullptr, 128, 128, W1t,
                                               nullptr, nullptr, b1, nullptr, hbf, n, 0,
                                               nullptr, nullptr);

    // two-level binned CSR build
    bin1_kernel<<<nb1, NT, 0, stream>>>(src, dst, m, gcur, bins);
    sbase_kernel<<<1, 256, 0, stream>>>(gcur, sbase, row_ptr, n, nsb, m);
    bin2_kernel<<<nsb, NT, 0, stream>>>(bins, gcur, sbase, row_ptr, csr, n);

    // layers 1,2: agg + GEMM(norm,relu), h in-place; layer 3: GEMM also applies W2 -> out
    for (int i = 0; i < 2; ++i) {
        agg_kernel<<<2048, NT, 0, stream>>>(hbf, row_ptr, csr, aggB, n);
        const unsigned short* Wlt = wt + 8192 + (size_t)i * 8192;
        const unsigned short* Wrt = Wlt + 4096;
        gemm_mfma<0, 0><<<gtiles, NT, 0, stream>>>(nullptr, aggB, 64, 64, Wlt,
                                                   hbf, Wrt, bl + (size_t)i * 64,
                                                   nullptr, hbf, n, 1, nullptr, nullptr);
    }
    agg_kernel<<<2048, NT, 0, stream>>>(hbf, row_ptr, csr, aggB, n);
    gemm_mfma<0, 1><<<gtiles, NT, 0, stream>>>(nullptr, aggB, 64, 64, wt + 8192 + 16384,
                                               hbf, wt + 8192 + 16384 + 4096, bl + 128,
                                               out, nullptr, n, 1, W2t, b2);
}

// Round 12
// 217.515 us; speedup vs baseline: 1.3778x; 1.0282x over previous
//
#include <hip/hip_runtime.h>
#include <hip/hip_bf16.h>

// GraphSAGE forward (R12 = R11 with 4-slot agg reverted + sbase folded into bin2):
//   two-level binned CSR build (bin1 -> bin2 w/ inline base scan) -> wconv -> lin1 (MFMA) ->
//   3x [agg (4-edge-slot gather-mean, bf16) + MFMA GEMM(norm,relu)]; layer-3 GEMM also does W2.

#define NT 256
#define BATCH 4096        // edges per bin1 block (NT * 16)
#define SBCAP 8192        // slots per super-bucket region (mean 6378 for m=1.25M)
#define HSTRIDE 72        // h3 LDS tile row stride (bf16): 144 B rows, 16B-aligned, 2-way banks (free)

typedef __attribute__((ext_vector_type(8))) short bf16x8;
typedef __attribute__((ext_vector_type(4))) float f32x4;

__device__ __forceinline__ float bfbits2f(unsigned short b) {
    return __uint_as_float(((unsigned)b) << 16);
}
__device__ __forceinline__ unsigned short f2bfbits(float v) {
    __hip_bfloat16 b = __float2bfloat16(v);
    return *reinterpret_cast<unsigned short*>(&b);
}

// ---------------- CSR build: two-level binning ----------------

__global__ __launch_bounds__(NT) void bin1_kernel(const int* __restrict__ src,
    const int* __restrict__ dst, int m, unsigned* __restrict__ gcur,
    unsigned* __restrict__ bins) {
    __shared__ unsigned hist[256];
    __shared__ unsigned gbase[256];
    const int t = threadIdx.x;
    const int base = blockIdx.x * BATCH;
    hist[t] = 0;
    __syncthreads();
    int d[16], s[16];
    const int e0 = base + t * 16;
    const bool full = (base + BATCH) <= m;
    if (full) {
        #pragma unroll
        for (int q = 0; q < 4; ++q) {
            const int4 dv = *(const int4*)&dst[e0 + q * 4];
            const int4 sv = *(const int4*)&src[e0 + q * 4];
            d[q*4+0]=dv.x; d[q*4+1]=dv.y; d[q*4+2]=dv.z; d[q*4+3]=dv.w;
            s[q*4+0]=sv.x; s[q*4+1]=sv.y; s[q*4+2]=sv.z; s[q*4+3]=sv.w;
        }
        #pragma unroll
        for (int q = 0; q < 16; ++q) atomicAdd(&hist[d[q] >> 9], 1u);
    } else {
        #pragma unroll
        for (int q = 0; q < 16; ++q) {
            const int e = e0 + q;
            if (e < m) { d[q] = dst[e]; s[q] = src[e]; atomicAdd(&hist[d[q] >> 9], 1u); }
            else d[q] = -1;
        }
    }
    __syncthreads();
    {
        const unsigned h = hist[t];
        gbase[t] = h ? atomicAdd(&gcur[t], h) : 0u;
        hist[t] = 0;                       // reuse as per-bucket cursor
    }
    __syncthreads();
    if (full) {
        #pragma unroll
        for (int q = 0; q < 16; ++q) {
            const int b = d[q] >> 9;
            const unsigned slot = gbase[b] + atomicAdd(&hist[b], 1u);
            bins[(size_t)b * SBCAP + slot] = ((unsigned)s[q] << 9) | (unsigned)(d[q] & 511);
        }
    } else {
        #pragma unroll
        for (int q = 0; q < 16; ++q) {
            if (d[q] >= 0) {
                const int b = d[q] >> 9;
                const unsigned slot = gbase[b] + atomicAdd(&hist[b], 1u);
                bins[(size_t)b * SBCAP + slot] = ((unsigned)s[q] << 9) | (unsigned)(d[q] & 511);
            }
        }
    }
}

// bin2: per super-bucket; computes its own base by scanning gcur (196 words) in-block.
__global__ __launch_bounds__(NT) void bin2_kernel(const unsigned* __restrict__ bins,
    const unsigned* __restrict__ gcur, int* __restrict__ row_ptr, int* __restrict__ csr,
    int n, int nsb, int m) {
    __shared__ unsigned hist[512];
    __shared__ unsigned off[512];
    __shared__ unsigned cur[512];
    __shared__ unsigned wsum[4];
    __shared__ unsigned gpre[256];
    const int k = blockIdx.x;
    const int t = threadIdx.x;
    const int lane = t & 63, wid = t >> 6;

    // inline exclusive scan of gcur[0..nsb) -> gpre
    {
        const unsigned gv = (t < nsb) ? gcur[t] : 0u;
        unsigned gx = gv;
        #pragma unroll
        for (int o = 1; o < 64; o <<= 1) {
            const unsigned tt = __shfl_up(gx, o, 64);
            if (lane >= o) gx += tt;
        }
        if (lane == 63) wsum[wid] = gx;
        __syncthreads();
        unsigned wo = 0;
        for (int w = 0; w < wid; ++w) wo += wsum[w];
        gpre[t] = wo + gx - gv;
        __syncthreads();
    }
    const int cnt = (int)gcur[k];
    const unsigned sb = gpre[k];
    if (k == 0 && t == 0) row_ptr[n] = m;

    const unsigned* reg = bins + (size_t)k * SBCAP;
    hist[2*t] = 0; hist[2*t+1] = 0;
    __syncthreads();
    for (int i = t; i < cnt; i += NT) atomicAdd(&hist[reg[i] & 511u], 1u);
    __syncthreads();
    const unsigned v0 = hist[2*t], v1 = hist[2*t+1];
    const unsigned ps = v0 + v1;
    unsigned x = ps;
    #pragma unroll
    for (int o = 1; o < 64; o <<= 1) {
        const unsigned tt = __shfl_up(x, o, 64);
        if (lane >= o) x += tt;
    }
    if (lane == 63) wsum[wid] = x;
    __syncthreads();
    unsigned woff = 0;
    for (int w = 0; w < wid; ++w) woff += wsum[w];
    const unsigned excl = woff + x - ps;
    off[2*t] = excl; off[2*t+1] = excl + v0;
    cur[2*t] = 0; cur[2*t+1] = 0;
    const int node = k * 512 + 2 * t;
    if (node < n)     row_ptr[node]     = (int)(sb + excl);
    if (node + 1 < n) row_ptr[node + 1] = (int)(sb + excl + v0);
    __syncthreads();
    for (int i = t; i < cnt; i += NT) {
        const unsigned u = reg[i];
        const unsigned l = u & 511u;
        const unsigned r = atomicAdd(&cur[l], 1u);
        csr[sb + off[l] + r] = (int)(u >> 9);
    }
}

// ---------------- weight convert+transpose: Wt[col][k] bf16 ----------------

__global__ void wconv_kernel(const float* __restrict__ W1, const float* __restrict__ Wl,
                             const float* __restrict__ Wr, const float* __restrict__ W2,
                             unsigned short* __restrict__ out) {
    int i = blockIdx.x * blockDim.x + threadIdx.x;
    if (i >= 36864) return;
    float v;
    if (i < 8192) {
        const int col = i >> 7, k = i & 127;
        v = W1[k * 64 + col];
    } else if (i < 32768) {
        const int j = i - 8192;
        const int mm = j >> 13, r = j & 8191;
        const int isR = (r >> 12) & 1, q = r & 4095;
        const int col = q >> 6, k = q & 63;
        v = (isR ? Wr : Wl)[mm * 4096 + k * 64 + col];
    } else {
        const int q = i - 32768;
        const int col = q >> 6, k = q & 63;
        v = W2[k * 64 + col];
    }
    out[i] = f2bfbits(v);
}

// ---------------- aggregation (4-slot): aggB[node] = bf16(mean over in-edges of h[src]) ----------------
// lane split: g=lane>>4 (edge slot), c=lane&15 (4 cols each). 4 edges per wave-load.

__global__ __launch_bounds__(NT) void agg_kernel(const unsigned short* __restrict__ h,
    const int* __restrict__ row_ptr, const int* __restrict__ csr,
    unsigned short* __restrict__ aggB, int n) {
    const int t = threadIdx.x;
    const int lane = t & 63;
    const int g = lane >> 4;
    const int c = lane & 15;
    const int gw = (blockIdx.x * NT + t) >> 6;
    const int nw = (gridDim.x * NT) >> 6;
    for (int node = gw; node < n; node += nw) {
        const int rs = row_ptr[node];
        const int re = row_ptr[node + 1];
        float a0 = 0.f, a1 = 0.f, a2 = 0.f, a3 = 0.f;
        int e = rs;
        for (; e + 16 <= re; e += 16) {
            const int s0 = csr[e + g];
            const int s1 = csr[e + 4 + g];
            const int s2 = csr[e + 8 + g];
            const int s3 = csr[e + 12 + g];
            const ushort4 v0 = *(const ushort4*)&h[(size_t)s0 * 64 + c * 4];
            const ushort4 v1 = *(const ushort4*)&h[(size_t)s1 * 64 + c * 4];
            const ushort4 v2 = *(const ushort4*)&h[(size_t)s2 * 64 + c * 4];
            const ushort4 v3 = *(const ushort4*)&h[(size_t)s3 * 64 + c * 4];
            a0 += (bfbits2f(v0.x) + bfbits2f(v1.x)) + (bfbits2f(v2.x) + bfbits2f(v3.x));
            a1 += (bfbits2f(v0.y) + bfbits2f(v1.y)) + (bfbits2f(v2.y) + bfbits2f(v3.y));
            a2 += (bfbits2f(v0.z) + bfbits2f(v1.z)) + (bfbits2f(v2.z) + bfbits2f(v3.z));
            a3 += (bfbits2f(v0.w) + bfbits2f(v1.w)) + (bfbits2f(v2.w) + bfbits2f(v3.w));
        }
        for (; e + 8 <= re; e += 8) {
            const int s0 = csr[e + g];
            const int s1 = csr[e + 4 + g];
            const ushort4 v0 = *(const ushort4*)&h[(size_t)s0 * 64 + c * 4];
            const ushort4 v1 = *(const ushort4*)&h[(size_t)s1 * 64 + c * 4];
            a0 += bfbits2f(v0.x) + bfbits2f(v1.x);
            a1 += bfbits2f(v0.y) + bfbits2f(v1.y);
            a2 += bfbits2f(v0.z) + bfbits2f(v1.z);
            a3 += bfbits2f(v0.w) + bfbits2f(v1.w);
        }
        for (; e + 4 <= re; e += 4) {
            const int s0 = csr[e + g];
            const ushort4 v0 = *(const ushort4*)&h[(size_t)s0 * 64 + c * 4];
            a0 += bfbits2f(v0.x);
            a1 += bfbits2f(v0.y);
            a2 += bfbits2f(v0.z);
            a3 += bfbits2f(v0.w);
        }
        const int r = re - e;
        if (g < r) {
            const int s0 = csr[e + g];
            const ushort4 v0 = *(const ushort4*)&h[(size_t)s0 * 64 + c * 4];
            a0 += bfbits2f(v0.x);
            a1 += bfbits2f(v0.y);
            a2 += bfbits2f(v0.z);
            a3 += bfbits2f(v0.w);
        }
        a0 += __shfl_xor(a0, 16, 64); a0 += __shfl_xor(a0, 32, 64);
        a1 += __shfl_xor(a1, 16, 64); a1 += __shfl_xor(a1, 32, 64);
        a2 += __shfl_xor(a2, 16, 64); a2 += __shfl_xor(a2, 32, 64);
        a3 += __shfl_xor(a3, 16, 64); a3 += __shfl_xor(a3, 32, 64);
        if (g == 0) {
            const float inv = (re > rs) ? (1.0f / (float)(re - rs)) : 0.0f;
            ushort4 o;
            o.x = f2bfbits(a0 * inv);
            o.y = f2bfbits(a1 * inv);
            o.z = f2bfbits(a2 * inv);
            o.w = f2bfbits(a3 * inv);
            *(ushort4*)&aggB[(size_t)node * 64 + c * 4] = o;
        }
    }
}

// ---------------- MFMA GEMM: C = A1@W1 [+ A2@W2] + bias; optional norm; LAST: + (C@W2t2 + b2) ----------------
// block = 4 waves, wave = 32 rows x 64 cols (2 row-tiles x 4 col-tiles of 16x16x32 mfma).
// C/D: col = lane&15, row = (lane>>4)*4 + reg.

template<int A1F32, int LAST>
__global__ __launch_bounds__(NT) void gemm_mfma(
    const float* __restrict__ A1f, const unsigned short* __restrict__ A1b,
    int ldA1, int K1, const unsigned short* __restrict__ W1t,
    const unsigned short* __restrict__ A2b, const unsigned short* __restrict__ W2t,
    const float* __restrict__ bias, float* __restrict__ outF,
    unsigned short* __restrict__ outB, int n, int do_norm,
    const unsigned short* __restrict__ W2t2, const float* __restrict__ b2) {
    const int t = threadIdx.x;
    const int lane = t & 63;
    const int w = t >> 6;
    const int r16 = lane & 15;
    const int g = lane >> 4;
    const int row0 = blockIdx.x * 128 + w * 32;

    f32x4 acc[2][4];
    #pragma unroll
    for (int i = 0; i < 2; ++i)
        #pragma unroll
        for (int j = 0; j < 4; ++j) {
            acc[i][j][0] = 0.f; acc[i][j][1] = 0.f; acc[i][j][2] = 0.f; acc[i][j][3] = 0.f;
        }

    int ra[2];
    #pragma unroll
    for (int rt = 0; rt < 2; ++rt) {
        int r = row0 + rt * 16 + r16;
        ra[rt] = (r < n) ? r : (n - 1);
    }

    #pragma unroll 1
    for (int kc = 0; kc < K1; kc += 32) {
        bf16x8 af[2];
        #pragma unroll
        for (int rt = 0; rt < 2; ++rt) {
            if (A1F32) {
                const float* p = &A1f[(size_t)ra[rt] * ldA1 + kc + g * 8];
                const float4 f0 = *(const float4*)p;
                const float4 f1 = *(const float4*)(p + 4);
                bf16x8 a;
                a[0] = (short)f2bfbits(f0.x); a[1] = (short)f2bfbits(f0.y);
                a[2] = (short)f2bfbits(f0.z); a[3] = (short)f2bfbits(f0.w);
                a[4] = (short)f2bfbits(f1.x); a[5] = (short)f2bfbits(f1.y);
                a[6] = (short)f2bfbits(f1.z); a[7] = (short)f2bfbits(f1.w);
                af[rt] = a;
            } else {
                af[rt] = *(const bf16x8*)&A1b[(size_t)ra[rt] * ldA1 + kc + g * 8];
            }
        }
        #pragma unroll
        for (int ct = 0; ct < 4; ++ct) {
            const bf16x8 bw = *(const bf16x8*)&W1t[(size_t)(ct * 16 + r16) * K1 + kc + g * 8];
            acc[0][ct] = __builtin_amdgcn_mfma_f32_16x16x32_bf16(af[0], bw, acc[0][ct], 0, 0, 0);
            acc[1][ct] = __builtin_amdgcn_mfma_f32_16x16x32_bf16(af[1], bw, acc[1][ct], 0, 0, 0);
        }
    }
    if (A2b) {
        #pragma unroll 1
        for (int kc = 0; kc < 64; kc += 32) {
            bf16x8 af[2];
            #pragma unroll
            for (int rt = 0; rt < 2; ++rt)
                af[rt] = *(const bf16x8*)&A2b[(size_t)ra[rt] * 64 + kc + g * 8];
            #pragma unroll
            for (int ct = 0; ct < 4; ++ct) {
                const bf16x8 bw = *(const bf16x8*)&W2t[(size_t)(ct * 16 + r16) * 64 + kc + g * 8];
                acc[0][ct] = __builtin_amdgcn_mfma_f32_16x16x32_bf16(af[0], bw, acc[0][ct], 0, 0, 0);
                acc[1][ct] = __builtin_amdgcn_mfma_f32_16x16x32_bf16(af[1], bw, acc[1][ct], 0, 0, 0);
            }
        }
    }

    float bcol[4];
    #pragma unroll
    for (int ct = 0; ct < 4; ++ct) bcol[ct] = bias[ct * 16 + r16];

    #pragma unroll
    for (int rt = 0; rt < 2; ++rt) {
        #pragma unroll
        for (int ct = 0; ct < 4; ++ct)
            #pragma unroll
            for (int reg = 0; reg < 4; ++reg) acc[rt][ct][reg] += bcol[ct];

        if (do_norm) {
            #pragma unroll
            for (int reg = 0; reg < 4; ++reg) {
                float ss = 0.f;
                #pragma unroll
                for (int ct = 0; ct < 4; ++ct) ss += acc[rt][ct][reg] * acc[rt][ct][reg];
                ss += __shfl_xor(ss, 1, 64);
                ss += __shfl_xor(ss, 2, 64);
                ss += __shfl_xor(ss, 4, 64);
                ss += __shfl_xor(ss, 8, 64);
                const float inv = 1.0f / fmaxf(sqrtf(ss), 1e-12f);
                #pragma unroll
                for (int ct = 0; ct < 4; ++ct)
                    acc[rt][ct][reg] = fmaxf(acc[rt][ct][reg] * inv, 0.0f);
            }
        }
    }

    if constexpr (!LAST) {
        #pragma unroll
        for (int rt = 0; rt < 2; ++rt) {
            const int rbase = row0 + rt * 16 + g * 4;
            #pragma unroll
            for (int reg = 0; reg < 4; ++reg) {
                const int rr = rbase + reg;
                if (rr < n) {
                    if (outB) {
                        #pragma unroll
                        for (int ct = 0; ct < 4; ++ct)
                            outB[(size_t)rr * 64 + ct * 16 + r16] = f2bfbits(acc[rt][ct][reg]);
                    } else {
                        #pragma unroll
                        for (int ct = 0; ct < 4; ++ct)
                            outF[(size_t)rr * 64 + ct * 16 + r16] = acc[rt][ct][reg];
                    }
                }
            }
        }
    } else {
        // stage h3 tile in LDS, then out = h3 @ W2t2 + b2 (f32)
        __shared__ unsigned short h3S[128][HSTRIDE];   // 18 KB
        #pragma unroll
        for (int rt = 0; rt < 2; ++rt) {
            #pragma unroll
            for (int reg = 0; reg < 4; ++reg) {
                const int lr = w * 32 + rt * 16 + g * 4 + reg;
                #pragma unroll
                for (int ct = 0; ct < 4; ++ct)
                    h3S[lr][ct * 16 + r16] = f2bfbits(acc[rt][ct][reg]);
            }
        }
        __syncthreads();
        f32x4 acc2[2][4];
        #pragma unroll
        for (int i = 0; i < 2; ++i)
            #pragma unroll
            for (int j = 0; j < 4; ++j) { acc2[i][j][0]=0.f; acc2[i][j][1]=0.f; acc2[i][j][2]=0.f; acc2[i][j][3]=0.f; }
        #pragma unroll
        for (int kc = 0; kc < 64; kc += 32) {
            bf16x8 af[2];
            #pragma unroll
            for (int rt = 0; rt < 2; ++rt)
                af[rt] = *(const bf16x8*)&h3S[w * 32 + rt * 16 + r16][kc + g * 8];
            #pragma unroll
            for (int ct = 0; ct < 4; ++ct) {
                const bf16x8 bw = *(const bf16x8*)&W2t2[(size_t)(ct * 16 + r16) * 64 + kc + g * 8];
                acc2[0][ct] = __builtin_amdgcn_mfma_f32_16x16x32_bf16(af[0], bw, acc2[0][ct], 0, 0, 0);
                acc2[1][ct] = __builtin_amdgcn_mfma_f32_16x16x32_bf16(af[1], bw, acc2[1][ct], 0, 0, 0);
            }
        }
        float b2c[4];
        #pragma unroll
        for (int ct = 0; ct < 4; ++ct) b2c[ct] = b2[ct * 16 + r16];
        #pragma unroll
        for (int rt = 0; rt < 2; ++rt) {
            const int rbase = row0 + rt * 16 + g * 4;
            #pragma unroll
            for (int reg = 0; reg < 4; ++reg) {
                const int rr = rbase + reg;
                if (rr < n) {
                    #pragma unroll
                    for (int ct = 0; ct < 4; ++ct)
                        outF[(size_t)rr * 64 + ct * 16 + r16] = acc2[rt][ct][reg] + b2c[ct];
                }
            }
        }
    }
}

// ---------------- launch ----------------

extern "C" void kernel_launch(void* const* d_in, const int* in_sizes, int n_in,
                              void* d_out, int out_size, void* d_ws, size_t ws_size,
                              hipStream_t stream) {
    const float* x  = (const float*)d_in[0];
    const int*   ei = (const int*)  d_in[1];
    const float* W1 = (const float*)d_in[2];
    const float* b1 = (const float*)d_in[3];
    const float* Wl = (const float*)d_in[4];
    const float* bl = (const float*)d_in[5];
    const float* Wr = (const float*)d_in[6];
    const float* W2 = (const float*)d_in[7];
    const float* b2 = (const float*)d_in[8];
    float* out = (float*)d_out;

    const int n = in_sizes[0] / 128;   // 100000
    const int m = in_sizes[1] / 2;     // 1250000
    const int* src = ei;
    const int* dst = ei + m;

    const int nsb = (n + 511) >> 9;    // 196 super-buckets (<= 256)

    char* ws = (char*)d_ws;
    size_t off = 0;
    auto alloc = [&](size_t bytes) -> void* {
        void* p = ws + off;
        off = (off + bytes + 255) & ~(size_t)255;
        return p;
    };
    unsigned short* aggB    = (unsigned short*)alloc((size_t)n * 64 * 2);
    unsigned short* hbf     = (unsigned short*)alloc((size_t)n * 64 * 2);
    int*            row_ptr = (int*)alloc((size_t)(n + 1) * sizeof(int));
    unsigned*       gcur    = (unsigned*)alloc((size_t)nsb * 4);
    unsigned*       bins    = (unsigned*)alloc((size_t)nsb * SBCAP * 4);
    int*            csr     = (int*)alloc((size_t)m * 4);
    unsigned short* wt      = (unsigned short*)alloc(36864 * 2);

    const unsigned short* W1t = wt;
    const unsigned short* W2t = wt + 32768;

    hipMemsetAsync(gcur, 0, (size_t)nsb * 4, stream);

    const int nb1 = (m + BATCH - 1) / BATCH;   // 306
    const int gtiles = (n + 127) / 128;        // 782

    wconv_kernel<<<144, NT, 0, stream>>>(W1, Wl, Wr, W2, wt);

    // h0 = x @ W1 + b1 -> hbf (bf16)
    gemm_mfma<1, 0><<<gtiles, NT, 0, stream>>>(x, nullptr, 128, 128, W1t,
                                               nullptr, nullptr, b1, nullptr, hbf, n, 0,
                                               nullptr, nullptr);

    // two-level binned CSR build
    bin1_kernel<<<nb1, NT, 0, stream>>>(src, dst, m, gcur, bins);
    bin2_kernel<<<nsb, NT, 0, stream>>>(bins, gcur, row_ptr, csr, n, nsb, m);

    // layers 1,2: agg + GEMM(norm,relu), h in-place; layer 3: GEMM also applies W2 -> out
    for (int i = 0; i < 2; ++i) {
        agg_kernel<<<2048, NT, 0, stream>>>(hbf, row_ptr, csr, aggB, n);
        const unsigned short* Wlt = wt + 8192 + (size_t)i * 8192;
        const unsigned short* Wrt = Wlt + 4096;
        gemm_mfma<0, 0><<<gtiles, NT, 0, stream>>>(nullptr, aggB, 64, 64, Wlt,
                                                   hbf, Wrt, bl + (size_t)i * 64,
                                                   nullptr, hbf, n, 1, nullptr, nullptr);
    }
    agg_kernel<<<2048, NT, 0, stream>>>(hbf, row_ptr, csr, aggB, n);
    gemm_mfma<0, 1><<<gtiles, NT, 0, stream>>>(nullptr, aggB, 64, 64, wt + 8192 + 16384,
                                               hbf, wt + 8192 + 16384 + 4096, bl + 128,
                                               out, nullptr, n, 1, W2t, b2);
}